// Round 1
// baseline (12189.385 us; speedup 1.0000x reference)
//
#include <hip/hip_runtime.h>
#include <hip/hip_bf16.h>
#include <stdint.h>

#define BDIM 256

constexpr int Bb   = 256;            // batch
constexpr int Tt   = 512;            // timesteps
constexpr int Hh   = 512;            // hidden
constexpr int NPOS = 128, NACT = 64, INPD = 192;
constexpr int KD   = Hh + INPD;      // 704 = [h | obs | act]
constexpr int NGRP = 8;              // batch groups
constexpr int BBr  = 32;             // batch rows per group
constexpr int NBLK = 32;             // blocks per group (h split)
constexpr int HHd  = 16;             // h dims per block
constexpr int KIT  = KD / 32;        // 22 MFMA K-iters
constexpr int APAD = KD + 8;         // 712: +8 bf16 pad -> 4-bank row shift, conflict-free-ish
constexpr int GPAD = 68;             // gates row stride (fp32), 68%32=4

typedef __attribute__((ext_vector_type(8))) short short8;
typedef __attribute__((ext_vector_type(4))) float f32x4;

__device__ __forceinline__ float bf2f(unsigned short u) {
  union { unsigned int i; float f; } v; v.i = ((unsigned int)u) << 16; return v.f;
}
__device__ __forceinline__ unsigned short f2bf(float f) {
  __hip_bfloat16 h = __float2bfloat16(f);
  return *reinterpret_cast<unsigned short*>(&h);
}
__device__ __forceinline__ float sigm(float x) { return 1.0f / (1.0f + __expf(-x)); }

__global__ void __launch_bounds__(BDIM, 1)
lstm_kernel(const float* __restrict__ obs, const float* __restrict__ actn,
            const float* __restrict__ h0, const float* __restrict__ c0,
            const float* __restrict__ W_ih, const float* __restrict__ W_hh,
            const float* __restrict__ b_ih, const float* __restrict__ b_hh,
            const float* __restrict__ W_out, const float* __restrict__ b_out,
            float* __restrict__ out, unsigned short* __restrict__ hbuf,
            unsigned int* __restrict__ cnt)
{
  // static LDS = 45568 + 8704 + 2048 + 2048 + 256 = 58624 B (<64K static limit);
  // +28672 dynamic pad at launch => 87296 B/block => hard 1 block/CU => all 256 resident
  __shared__ __align__(16) unsigned short act_s[BBr * APAD]; // [32][712] bf16: h(512)|obs(128)|act(64)
  __shared__ float gates_s[BBr * GPAD];                      // [32][68] fp32
  __shared__ float c_s[BBr * HHd];                           // [32][16] fp32 cell state (block-local)
  __shared__ float wout_s[Hh];
  __shared__ float bias_s[64];                               // b_ih+b_hh for this block's 64 gate rows

  const int tid  = threadIdx.x;
  const int g    = blockIdx.x & 7;   // batch group: %8 -> group-mates share an XCD (heuristic)
  const int jb   = blockIdx.x >> 3;  // h-slice 0..31
  const int wv   = tid >> 6, lane = tid & 63;
  const int wm   = wv >> 1;          // M-tile (batch 16-row tile)
  const int wn2  = (wv & 1) * 2;     // N-tile pair base
  const int cl   = lane & 15, qd = lane >> 4;

  unsigned short* hb0 = hbuf;
  unsigned short* hb1 = hbuf + (size_t)Bb * Hh;
  unsigned int* mycnt = cnt + g * 32;   // 128B-spaced counter per group

  // ---- W slice -> register-resident bf16 B-fragments (one-time) ----
  // block's gate rows: R = q*512 + jb*16 + r  (q=gate i/f/g/o, r=0..15); K order [W_hh | W_ih]
  short8 wfrag[2][KIT];
  #pragma unroll
  for (int tt = 0; tt < 2; ++tt) {
    const int nl = (wn2 + tt) * 16 + cl;
    const int q = nl >> 4, r = nl & 15;
    const int R = q * Hh + jb * HHd + r;
    const float* whh = W_hh + (size_t)R * Hh;
    const float* wih = W_ih + (size_t)R * INPD;
    #pragma unroll
    for (int kk = 0; kk < KIT; ++kk) {
      const int k0 = kk * 32 + qd * 8;
      short8 s;
      #pragma unroll
      for (int e = 0; e < 8; ++e) {
        const int k = k0 + e;
        const float f = (k < Hh) ? whh[k] : wih[k - Hh];
        s[e] = (short)f2bf(f);
      }
      wfrag[tt][kk] = s;
    }
  }

  if (tid < 64) {
    const int R = (tid >> 4) * Hh + jb * HHd + (tid & 15);
    bias_s[tid] = b_ih[R] + b_hh[R];
  }
  for (int i = tid; i < Hh; i += BDIM) wout_s[i] = W_out[i];
  for (int i = tid; i < BBr * HHd; i += BDIM) {
    const int m = i >> 4, r = i & 15;
    const size_t gi = (size_t)(g * BBr + m) * Hh + jb * HHd + r;
    c_s[i] = c0[gi];
    hb0[gi] = f2bf(h0[gi]);   // stage h_{-1}
  }
  const float bout = b_out[0];

  // ---- group barrier: monotonic counter, agent scope (cross-XCD safe) ----
  unsigned int phase = 0;
  auto barrier = [&]() {
    __builtin_amdgcn_fence(__ATOMIC_RELEASE, "agent");
    __syncthreads();
    ++phase;
    if (tid == 0) {
      __hip_atomic_fetch_add(mycnt, 1u, __ATOMIC_RELAXED, __HIP_MEMORY_SCOPE_AGENT);
      const unsigned int tgt = phase * NBLK;
      unsigned int spins = 0;
      while (__hip_atomic_load(mycnt, __ATOMIC_RELAXED, __HIP_MEMORY_SCOPE_AGENT) < tgt) {
        __builtin_amdgcn_s_sleep(1);
        if (++spins > 500000u) break;   // safety valve: wrong-not-hung on pathological stall
      }
    }
    __syncthreads();
    __builtin_amdgcn_fence(__ATOMIC_ACQUIRE, "agent");
  };

  barrier();   // h0 visible to whole group

  for (int t = 0; t < Tt; ++t) {
    const unsigned short* hsrc = (t & 1) ? hb1 : hb0;  // holds h_{t-1}
    unsigned short* hdst       = (t & 1) ? hb0 : hb1;  // receives h_t

    // ---- stage activations into LDS ----
    {
      const unsigned short* src = hsrc + (size_t)g * BBr * Hh;
      for (int i = tid; i < BBr * (Hh / 8); i += BDIM) {        // 2048 x 16B
        const int m = i >> 6, cs = i & 63;
        const uint4 v = *(const uint4*)(src + (size_t)m * Hh + cs * 8);
        *(uint4*)(&act_s[m * APAD + cs * 8]) = v;
      }
      for (int i = tid; i < BBr * (NPOS / 4); i += BDIM) {      // obs fp32 -> bf16
        const int m = i >> 5, c4 = i & 31;
        const float4 v = *(const float4*)(obs + ((size_t)(g * BBr + m) * Tt + t) * NPOS + c4 * 4);
        uint2 p;
        p.x = (unsigned)f2bf(v.x) | ((unsigned)f2bf(v.y) << 16);
        p.y = (unsigned)f2bf(v.z) | ((unsigned)f2bf(v.w) << 16);
        *(uint2*)(&act_s[m * APAD + Hh + c4 * 4]) = p;
      }
      for (int i = tid; i < BBr * (NACT / 4); i += BDIM) {      // action fp32 -> bf16
        const int m = i >> 4, c4 = i & 15;
        const float4 v = *(const float4*)(actn + ((size_t)(g * BBr + m) * Tt + t) * NACT + c4 * 4);
        uint2 p;
        p.x = (unsigned)f2bf(v.x) | ((unsigned)f2bf(v.y) << 16);
        p.y = (unsigned)f2bf(v.z) | ((unsigned)f2bf(v.w) << 16);
        *(uint2*)(&act_s[m * APAD + Hh + NPOS + c4 * 4]) = p;
      }
    }
    __syncthreads();

    // ---- gates = act @ W^T + bias, via 16x16x32 bf16 MFMA ----
    f32x4 acc0, acc1;
    {
      const float b0v = bias_s[wn2 * 16 + cl];        // D col = lane&15 = gate row n
      const float b1v = bias_s[(wn2 + 1) * 16 + cl];
      acc0 = (f32x4){b0v, b0v, b0v, b0v};
      acc1 = (f32x4){b1v, b1v, b1v, b1v};
    }
    const unsigned short* arow = &act_s[(wm * 16 + cl) * APAD + qd * 8];
    #pragma unroll
    for (int kk = 0; kk < KIT; ++kk) {
      const short8 a = *(const short8*)(arow + kk * 32);
      acc0 = __builtin_amdgcn_mfma_f32_16x16x32_bf16(a, wfrag[0][kk], acc0, 0, 0, 0);
      acc1 = __builtin_amdgcn_mfma_f32_16x16x32_bf16(a, wfrag[1][kk], acc1, 0, 0, 0);
    }
    // D layout: row(m) = qd*4+reg, col(n) = lane&15
    #pragma unroll
    for (int tt = 0; tt < 2; ++tt) {
      const f32x4 a = tt ? acc1 : acc0;
      #pragma unroll
      for (int rg = 0; rg < 4; ++rg)
        gates_s[(wm * 16 + qd * 4 + rg) * GPAD + (wn2 + tt) * 16 + cl] = a[rg];
    }
    __syncthreads();

    // ---- LSTM elementwise (PyTorch gate order i,f,g,o) ----
    for (int i = tid; i < BBr * HHd; i += BDIM) {
      const int m = i >> 4, r = i & 15;
      const float gi = gates_s[m * GPAD + r];
      const float gf = gates_s[m * GPAD + 16 + r];
      const float gg = gates_s[m * GPAD + 32 + r];
      const float go = gates_s[m * GPAD + 48 + r];
      const float cp = c_s[i];
      const float iv = sigm(gi), fv = sigm(gf);
      const float gv = tanhf(gg), ov = sigm(go);
      const float cn = fv * cp + iv * gv;
      const float hn = ov * tanhf(cn);
      c_s[i] = cn;
      hdst[(size_t)(g * BBr + m) * Hh + jb * HHd + r] = f2bf(hn);
    }

    // ---- out[:, t-1] from h_{t-1} sitting in act_s (j==0 block only) ----
    if (jb == 0 && t > 0) {
      const int m = tid >> 3, l8 = tid & 7;
      const unsigned short* hr = &act_s[m * APAD + l8 * 64];
      const float* wr = &wout_s[l8 * 64];
      float sum = 0.f;
      #pragma unroll 8
      for (int e = 0; e < 64; ++e) sum += bf2f(hr[e]) * wr[e];
      #pragma unroll
      for (int d = 4; d > 0; d >>= 1) sum += __shfl_down(sum, d, 64);
      if (l8 == 0) out[(size_t)(g * BBr + m) * Tt + (t - 1)] = sum + bout;
    }

    barrier();
  }

  // final column: h_{T-1} lives in hb0 (T even), visible after last barrier
  if (jb == 0) {
    const int m = tid >> 3, l8 = tid & 7;
    const unsigned short* hr = hb0 + (size_t)(g * BBr + m) * Hh + l8 * 64;
    float sum = 0.f;
    for (int e = 0; e < 64; ++e) sum += bf2f(hr[e]) * wout_s[l8 * 64 + e];
    #pragma unroll
    for (int d = 4; d > 0; d >>= 1) sum += __shfl_down(sum, d, 64);
    if (l8 == 0) out[(size_t)(g * BBr + m) * Tt + (Tt - 1)] = sum + bout;
  }
}

extern "C" void kernel_launch(void* const* d_in, const int* in_sizes, int n_in,
                              void* d_out, int out_size, void* d_ws, size_t ws_size,
                              hipStream_t stream) {
  const float* obs   = (const float*)d_in[0];
  const float* actn  = (const float*)d_in[1];
  const float* h0    = (const float*)d_in[2];
  const float* c0    = (const float*)d_in[3];
  const float* W_ih  = (const float*)d_in[4];
  const float* W_hh  = (const float*)d_in[5];
  const float* b_ih  = (const float*)d_in[6];
  const float* b_hh  = (const float*)d_in[7];
  const float* W_out = (const float*)d_in[8];
  const float* b_out = (const float*)d_in[9];
  float* out = (float*)d_out;

  // ws layout: hbuf[2][256*512] bf16 (524288 B) | counters 8*128 B. Needs ~525.3 KB.
  unsigned short* hbuf = (unsigned short*)d_ws;
  const size_t hbytes = (size_t)2 * Bb * Hh * sizeof(unsigned short);
  unsigned int* cnt = (unsigned int*)((char*)d_ws + hbytes);

  hipMemsetAsync(cnt, 0, NGRP * 32 * sizeof(unsigned int), stream);  // ws is 0xAA-poisoned

  // dummy dynamic LDS pad: total 87.3 KB/block -> hard 1 block/CU -> 256 blocks co-resident
  hipFuncSetAttribute((const void*)lstm_kernel,
                      hipFuncAttributeMaxDynamicSharedMemorySize, 28672);
  hipLaunchKernelGGL(lstm_kernel, dim3(256), dim3(BDIM), 28672, stream,
                     obs, actn, h0, c0, W_ih, W_hh, b_ih, b_hh, W_out, b_out,
                     out, hbuf, cnt);
}

// Round 2
// 2399.596 us; speedup vs baseline: 5.0798x; 5.0798x over previous
//
#include <hip/hip_runtime.h>
#include <hip/hip_bf16.h>
#include <stdint.h>

#define BDIM 512

constexpr int Bb   = 256;            // batch
constexpr int Tt   = 512;            // timesteps
constexpr int Hh   = 512;            // hidden
constexpr int NPOS = 128, NACT = 64, INPD = 192;
constexpr int KD   = Hh + INPD;      // 704 = [h | obs | act]
constexpr int NGRP = 8;              // batch groups
constexpr int BBr  = 32;             // batch rows per group
constexpr int NBLK = 32;             // blocks per group (h split)
constexpr int HHd  = 16;             // h dims per block
constexpr int KIT  = KD / 32;        // 22 MFMA K-iters
constexpr int APAD = KD + 8;         // 712 shorts: row shift breaks pow2 stride
constexpr int GPAD = 68;             // gates row stride (fp32)

typedef __attribute__((ext_vector_type(8))) short short8;
typedef __attribute__((ext_vector_type(4))) float f32x4;
typedef __attribute__((ext_vector_type(4))) unsigned int u32x4;

__device__ __forceinline__ float bf2f(unsigned short u) {
  union { unsigned int i; float f; } v; v.i = ((unsigned int)u) << 16; return v.f;
}
__device__ __forceinline__ unsigned short f2bf(float f) {
  __hip_bfloat16 h = __float2bfloat16(f);
  return *reinterpret_cast<unsigned short*>(&h);
}
__device__ __forceinline__ float sigm(float x) { return 1.0f / (1.0f + __expf(-x)); }

// ---- cache-bypassing (device-coherent) global ops: the h-exchange never
// becomes L2-dirty, so NO buffer_wbl2/buffer_inv fences are needed. ----
__device__ __forceinline__ void store_wt16(void* p, u32x4 v) {
  asm volatile("global_store_dwordx4 %0, %1, off sc0 sc1" :: "v"(p), "v"(v) : "memory");
}
__device__ __forceinline__ u32x4 load_wt16(const void* p) {
  u32x4 r;
  asm volatile("global_load_dwordx4 %0, %1, off sc0 sc1" : "=v"(r) : "v"(p) : "memory");
  return r;
}
__device__ __forceinline__ void store_wt2(void* p, unsigned short v) {
  unsigned int w = v;
  asm volatile("global_store_short %0, %1, off sc0 sc1" :: "v"(p), "v"(w) : "memory");
}
__device__ __forceinline__ void waitvm0() {
  asm volatile("s_waitcnt vmcnt(0)" ::: "memory");
}

__global__ void __launch_bounds__(BDIM, 2)
lstm_kernel(const float* __restrict__ obs, const float* __restrict__ actn,
            const float* __restrict__ h0, const float* __restrict__ c0,
            const float* __restrict__ W_ih, const float* __restrict__ W_hh,
            const float* __restrict__ b_ih, const float* __restrict__ b_hh,
            const float* __restrict__ W_out, const float* __restrict__ b_out,
            float* __restrict__ out, unsigned short* __restrict__ hbuf,
            unsigned int* __restrict__ cnt)
{
  // static LDS = 45568+8704+2048+2048+256 = 58624 B; +28672 dynamic pad
  // => 87296 B/block => hard 1 block/CU => all 256 blocks co-resident (spin-safe)
  __shared__ __align__(16) unsigned short act_s[BBr * APAD]; // [32][712] bf16: h|obs|act
  __shared__ float gates_s[BBr * GPAD];                      // [32][68] fp32
  __shared__ float c_s[BBr * HHd];                           // [32][16] fp32 cell state
  __shared__ float wout_s[Hh];
  __shared__ float bias_s[64];

  const int tid  = threadIdx.x;
  const int g    = blockIdx.x & 7;   // batch group (group-mates land on one XCD — perf heuristic)
  const int jb   = blockIdx.x >> 3;  // h-slice 0..31
  const int wv   = tid >> 6, lane = tid & 63;
  const int wm   = wv >> 2;          // M-tile (batch 16-row tile) 0..1
  const int wn   = wv & 3;           // N-tile = gate type 0..3
  const int cl   = lane & 15, qd = lane >> 4;

  unsigned short* hb0 = hbuf;
  unsigned short* hb1 = hbuf + (size_t)Bb * Hh;
  unsigned int* mycnt = cnt + g * 32;

  // ---- W slice -> register-resident bf16 MFMA B-fragments (one-time) ----
  // this wave's 16 gate rows: R = wn*512 + jb*16 + cl ; K order [W_hh | W_ih]
  short8 wfrag[KIT];
  {
    const int R = wn * Hh + jb * HHd + cl;
    const float* whh = W_hh + (size_t)R * Hh;
    const float* wih = W_ih + (size_t)R * INPD;
    #pragma unroll
    for (int kk = 0; kk < KIT; ++kk) {
      const int k0 = kk * 32 + qd * 8;
      short8 s;
      #pragma unroll
      for (int e = 0; e < 8; ++e) {
        const int k = k0 + e;
        const float f = (k < Hh) ? whh[k] : wih[k - Hh];
        s[e] = (short)f2bf(f);
      }
      wfrag[kk] = s;
    }
  }

  if (tid < 64) {
    const int R = (tid >> 4) * Hh + jb * HHd + (tid & 15);
    bias_s[tid] = b_ih[R] + b_hh[R];
  }
  for (int i = tid; i < Hh; i += BDIM) wout_s[i] = W_out[i];
  {
    const int i = tid;                       // BDIM == BBr*HHd == 512
    const int m = i >> 4, r = i & 15;
    const size_t gi = (size_t)(g * BBr + m) * Hh + jb * HHd + r;
    c_s[i] = c0[gi];
    store_wt2(hb0 + gi, f2bf(h0[gi]));       // h_{-1}, write-through coherent
  }
  const float bout = b_out[0];

  // ---- group barrier: relaxed monotonic counter (no cache-maintenance ops).
  // Ordering: waitvm0 drains write-through stores to the coherence point. ----
  unsigned int phase = 0;
  auto barrier = [&]() {
    waitvm0();
    __syncthreads();
    ++phase;
    if (tid == 0) {
      __hip_atomic_fetch_add(mycnt, 1u, __ATOMIC_RELAXED, __HIP_MEMORY_SCOPE_AGENT);
      const unsigned int tgt = phase * NBLK;
      unsigned int spins = 0;
      while (__hip_atomic_load(mycnt, __ATOMIC_RELAXED, __HIP_MEMORY_SCOPE_AGENT) < tgt) {
        __builtin_amdgcn_s_sleep(2);
        if (++spins > 2000000u) break;   // wrong-not-hung safety valve
      }
    }
    __syncthreads();
  };

  barrier();   // h0 visible group-wide

  for (int t = 0; t < Tt; ++t) {
    const unsigned short* hsrc = (t & 1) ? hb1 : hb0;  // h_{t-1}
    unsigned short* hdst       = (t & 1) ? hb0 : hb1;  // h_t

    // ---- stage h (coherent loads -> regs), obs/act (cached) -> LDS ----
    u32x4 hv[4];
    {
      const unsigned short* src = hsrc + (size_t)g * BBr * Hh;
      #pragma unroll
      for (int it = 0; it < 4; ++it) {
        const int i = tid + BDIM * it;                 // 2048 x 16B chunks
        hv[it] = load_wt16(src + ((i >> 6) * Hh + (i & 63) * 8));
      }
    }
    #pragma unroll
    for (int it = 0; it < 2; ++it) {                   // obs fp32 -> bf16
      const int i = tid + BDIM * it;
      const int m = i >> 5, c4 = i & 31;
      const float4 v = *(const float4*)(obs + ((size_t)(g * BBr + m) * Tt + t) * NPOS + c4 * 4);
      uint2 p;
      p.x = (unsigned)f2bf(v.x) | ((unsigned)f2bf(v.y) << 16);
      p.y = (unsigned)f2bf(v.z) | ((unsigned)f2bf(v.w) << 16);
      *(uint2*)(&act_s[m * APAD + Hh + c4 * 4]) = p;
    }
    {
      const int i = tid;                               // action fp32 -> bf16
      const int m = i >> 4, c4 = i & 15;
      const float4 v = *(const float4*)(actn + ((size_t)(g * BBr + m) * Tt + t) * NACT + c4 * 4);
      uint2 p;
      p.x = (unsigned)f2bf(v.x) | ((unsigned)f2bf(v.y) << 16);
      p.y = (unsigned)f2bf(v.z) | ((unsigned)f2bf(v.w) << 16);
      *(uint2*)(&act_s[m * APAD + Hh + NPOS + c4 * 4]) = p;
    }
    waitvm0();
    #pragma unroll
    for (int it = 0; it < 4; ++it) {
      const int i = tid + BDIM * it;
      *(u32x4*)(&act_s[(i >> 6) * APAD + (i & 63) * 8]) = hv[it];
    }
    __syncthreads();

    // ---- gates = act @ W^T + bias (16x16x32 bf16 MFMA, 22 K-iters) ----
    f32x4 acc;
    { const float bv = bias_s[wn * 16 + cl]; acc = (f32x4){bv, bv, bv, bv}; }
    const unsigned short* arow = &act_s[(wm * 16 + cl) * APAD + qd * 8];
    #pragma unroll
    for (int kk = 0; kk < KIT; ++kk) {
      const short8 a = *(const short8*)(arow + kk * 32);
      acc = __builtin_amdgcn_mfma_f32_16x16x32_bf16(a, wfrag[kk], acc, 0, 0, 0);
    }
    #pragma unroll
    for (int rg = 0; rg < 4; ++rg)                     // D: row=qd*4+rg, col=cl
      gates_s[(wm * 16 + qd * 4 + rg) * GPAD + wn * 16 + cl] = acc[rg];
    __syncthreads();

    // ---- LSTM elementwise (i,f,g,o), h_t out via write-through stores ----
    {
      const int i = tid;
      const int m = i >> 4, r = i & 15;
      const float gi = gates_s[m * GPAD + r];
      const float gf = gates_s[m * GPAD + 16 + r];
      const float gg = gates_s[m * GPAD + 32 + r];
      const float go = gates_s[m * GPAD + 48 + r];
      const float cp = c_s[i];
      const float iv = sigm(gi), fv = sigm(gf);
      const float gv = tanhf(gg), ov = sigm(go);
      const float cn = fv * cp + iv * gv;
      const float hn = ov * tanhf(cn);
      c_s[i] = cn;
      store_wt2(hdst + (size_t)(g * BBr + m) * Hh + jb * HHd + r, f2bf(hn));
    }

    // ---- out[:, t-1] from h_{t-1} in act_s (j==0 block) ----
    if (jb == 0 && t > 0 && tid < 256) {
      const int m = tid >> 3, l8 = tid & 7;
      const unsigned short* hr = &act_s[m * APAD + l8 * 64];
      const float* wr = &wout_s[l8 * 64];
      float sum = 0.f;
      #pragma unroll 8
      for (int e = 0; e < 64; ++e) sum += bf2f(hr[e]) * wr[e];
      sum += __shfl_down(sum, 4, 64);
      sum += __shfl_down(sum, 2, 64);
      sum += __shfl_down(sum, 1, 64);
      if (l8 == 0) out[(size_t)(g * BBr + m) * Tt + (t - 1)] = sum + bout;
    }

    barrier();
  }

  // final column from h_{T-1} (in hb0; T even), coherent loads
  if (jb == 0 && tid < 256) {
    const int m = tid >> 3, l8 = tid & 7;
    const unsigned short* hr = hb0 + (size_t)(g * BBr + m) * Hh + l8 * 64;
    u32x4 hvv[8];
    #pragma unroll
    for (int it = 0; it < 8; ++it) hvv[it] = load_wt16(hr + it * 8);
    waitvm0();
    float sum = 0.f;
    #pragma unroll
    for (int it = 0; it < 8; ++it) {
      #pragma unroll
      for (int j = 0; j < 4; ++j) {
        const unsigned u = hvv[it][j];
        sum += bf2f((unsigned short)(u & 0xffffu)) * wout_s[l8 * 64 + it * 8 + j * 2];
        sum += bf2f((unsigned short)(u >> 16))     * wout_s[l8 * 64 + it * 8 + j * 2 + 1];
      }
    }
    sum += __shfl_down(sum, 4, 64);
    sum += __shfl_down(sum, 2, 64);
    sum += __shfl_down(sum, 1, 64);
    if (l8 == 0) out[(size_t)(g * BBr + m) * Tt + (Tt - 1)] = sum + bout;
  }
}

extern "C" void kernel_launch(void* const* d_in, const int* in_sizes, int n_in,
                              void* d_out, int out_size, void* d_ws, size_t ws_size,
                              hipStream_t stream) {
  const float* obs   = (const float*)d_in[0];
  const float* actn  = (const float*)d_in[1];
  const float* h0    = (const float*)d_in[2];
  const float* c0    = (const float*)d_in[3];
  const float* W_ih  = (const float*)d_in[4];
  const float* W_hh  = (const float*)d_in[5];
  const float* b_ih  = (const float*)d_in[6];
  const float* b_hh  = (const float*)d_in[7];
  const float* W_out = (const float*)d_in[8];
  const float* b_out = (const float*)d_in[9];
  float* out = (float*)d_out;

  unsigned short* hbuf = (unsigned short*)d_ws;            // 2 x 256x512 bf16
  const size_t hbytes = (size_t)2 * Bb * Hh * sizeof(unsigned short);
  unsigned int* cnt = (unsigned int*)((char*)d_ws + hbytes);

  hipMemsetAsync(cnt, 0, NGRP * 32 * sizeof(unsigned int), stream);

  hipFuncSetAttribute((const void*)lstm_kernel,
                      hipFuncAttributeMaxDynamicSharedMemorySize, 28672);
  hipLaunchKernelGGL(lstm_kernel, dim3(256), dim3(BDIM), 28672, stream,
                     obs, actn, h0, c0, W_ih, W_hh, b_ih, b_hh, W_out, b_out,
                     out, hbuf, cnt);
}

// Round 3
// 1944.024 us; speedup vs baseline: 6.2702x; 1.2343x over previous
//
#include <hip/hip_runtime.h>
#include <hip/hip_bf16.h>
#include <stdint.h>

#define BDIM 512

constexpr int Bb   = 256;            // batch
constexpr int Tt   = 512;            // timesteps
constexpr int Hh   = 512;            // hidden
constexpr int NPOS = 128, NACT = 64, INPD = 192;
constexpr int NGRP = 8;              // batch groups
constexpr int BBr  = 32;             // batch rows per group
constexpr int NBLK = 32;             // blocks per group (h split)
constexpr int HHd  = 16;             // h dims per block
constexpr int KITH = Hh / 32;        // 16 h-part MFMA K-iters
constexpr int KITX = INPD / 32;      // 6  x-part MFMA K-iters
constexpr int HPAD = Hh + 8;         // 520 shorts/row
constexpr int XPAD = INPD + 8;       // 200 shorts/row
constexpr int GPAD = 68;             // gates row stride (fp32)

typedef __attribute__((ext_vector_type(8))) short short8;
typedef __attribute__((ext_vector_type(4))) float f32x4;
typedef __attribute__((ext_vector_type(4))) unsigned int u32x4;

__device__ __forceinline__ float bf2f(unsigned short u) {
  union { unsigned int i; float f; } v; v.i = ((unsigned int)u) << 16; return v.f;
}
__device__ __forceinline__ unsigned short f2bf(float f) {
  __hip_bfloat16 h = __float2bfloat16(f);
  return *reinterpret_cast<unsigned short*>(&h);
}
__device__ __forceinline__ float sigm(float x) { return 1.0f / (1.0f + __expf(-x)); }
__device__ __forceinline__ float tanh_fast(float x) {
  return 1.0f - 2.0f / (1.0f + __expf(2.0f * x));   // saturates correctly at +-inf
}

// device-coherent (L1/L2-bypass) global ops — exchanged data never becomes
// L2-dirty, so no cache-maintenance fences are ever needed.
__device__ __forceinline__ void store_wt16(void* p, u32x4 v) {
  asm volatile("global_store_dwordx4 %0, %1, off sc0 sc1" :: "v"(p), "v"(v) : "memory");
}
__device__ __forceinline__ u32x4 load_wt16(const void* p) {
  u32x4 r;
  asm volatile("global_load_dwordx4 %0, %1, off sc0 sc1" : "=v"(r) : "v"(p) : "memory");
  return r;
}
__device__ __forceinline__ void store_wt2(void* p, unsigned short v) {
  unsigned int w = v;
  asm volatile("global_store_short %0, %1, off sc0 sc1" :: "v"(p), "v"(w) : "memory");
}
__device__ __forceinline__ void store_wt4(void* p, unsigned int v) {
  asm volatile("global_store_dword %0, %1, off sc0 sc1" :: "v"(p), "v"(v) : "memory");
}
__device__ __forceinline__ unsigned int load_wt4(const void* p) {
  unsigned int r;
  asm volatile("global_load_dword %0, %1, off sc0 sc1" : "=v"(r) : "v"(p) : "memory");
  return r;
}
__device__ __forceinline__ void waitvm0() {
  asm volatile("s_waitcnt vmcnt(0)" ::: "memory");
}

__global__ void __launch_bounds__(BDIM, 2)
lstm_kernel(const float* __restrict__ obs, const float* __restrict__ actn,
            const float* __restrict__ h0, const float* __restrict__ c0,
            const float* __restrict__ W_ih, const float* __restrict__ W_hh,
            const float* __restrict__ b_ih, const float* __restrict__ b_hh,
            const float* __restrict__ W_out, const float* __restrict__ b_out,
            float* __restrict__ out, unsigned short* __restrict__ hbuf,
            unsigned int* __restrict__ flags)
{
  // static LDS = 33280+12800+8704+2048+2048+256 = 59136 B; +28672 dynamic pad
  // => 87808 B/block => hard 1 block/CU => all 256 blocks co-resident (spin-safe)
  __shared__ __align__(16) unsigned short h_s[BBr * HPAD]; // [32][520] bf16, dims 0..511 contiguous
  __shared__ __align__(16) unsigned short x_s[BBr * XPAD]; // [32][200] bf16: obs|act
  __shared__ float gates_s[BBr * GPAD];                    // [32][68] fp32
  __shared__ float c_s[BBr * HHd];                         // [32][16] fp32 cell state
  __shared__ float wout_s[Hh];
  __shared__ float bias_s[64];

  const int tid  = threadIdx.x;
  const int g    = blockIdx.x & 7;   // batch group (XCD-mate heuristic only)
  const int jb   = blockIdx.x >> 3;  // h-slice 0..31
  const int wv   = tid >> 6, lane = tid & 63;
  const int wm   = wv >> 2;          // M-tile (batch 16-row tile) 0..1
  const int wn   = wv & 3;           // N-tile = gate type 0..3
  const int cl   = lane & 15, qd = lane >> 4;

  // hbuf layout (block-major): elem((g,jb),row,r) = ((g*32+jb)*32+row)*16 + r
  unsigned short* hb0 = hbuf;
  unsigned short* hb1 = hbuf + (size_t)Bb * Hh;
  const size_t slotbase = (size_t)(g * NBLK + jb) * (BBr * HHd);  // this block's 1KB slice
  const size_t grpbase  = (size_t)g * NBLK * (BBr * HHd);         // group's 32KB region
  unsigned int* myflag = flags + (size_t)(g * NBLK + jb) * 32;    // 128B spacing
  const unsigned int* pollflag = flags + (size_t)(g * NBLK + (lane & 31)) * 32;

  // ---- W slice -> register-resident bf16 MFMA B-fragments (one-time) ----
  // wave's 16 gate rows: R = wn*512 + jb*16 + cl ; K = [W_hh(0..511) | W_ih(512..703)]
  short8 wfrag[KITH + KITX];
  {
    const int R = wn * Hh + jb * HHd + cl;
    const float* whh = W_hh + (size_t)R * Hh;
    const float* wih = W_ih + (size_t)R * INPD;
    #pragma unroll
    for (int kk = 0; kk < KITH + KITX; ++kk) {
      const int k0 = kk * 32 + qd * 8;
      short8 s;
      #pragma unroll
      for (int e = 0; e < 8; ++e) {
        const int k = k0 + e;
        const float f = (k < Hh) ? whh[k] : wih[k - Hh];
        s[e] = (short)f2bf(f);
      }
      wfrag[kk] = s;
    }
  }

  if (tid < 64) {
    const int R = (tid >> 4) * Hh + jb * HHd + (tid & 15);
    bias_s[tid] = b_ih[R] + b_hh[R];
  }
  for (int i = tid; i < Hh; i += BDIM) wout_s[i] = W_out[i];
  {
    const int m = tid >> 4, r = tid & 15;
    const size_t gi = (size_t)(g * BBr + m) * Hh + jb * HHd + r;
    c_s[tid] = c0[gi];
    store_wt2(hb0 + slotbase + tid, f2bf(h0[gi]));   // contiguous 1KB slice
  }
  const float bout = b_out[0];

  // ---- helpers ----
  auto stage_x = [&](int t) {   // obs/act fp32 -> bf16 -> x_s
    #pragma unroll
    for (int it = 0; it < 2; ++it) {
      const int i = tid + BDIM * it;
      const int m = i >> 5, c4 = i & 31;
      const float4 v = *(const float4*)(obs + ((size_t)(g * BBr + m) * Tt + t) * NPOS + c4 * 4);
      uint2 p;
      p.x = (unsigned)f2bf(v.x) | ((unsigned)f2bf(v.y) << 16);
      p.y = (unsigned)f2bf(v.z) | ((unsigned)f2bf(v.w) << 16);
      *(uint2*)(&x_s[m * XPAD + c4 * 4]) = p;
    }
    {
      const int m = tid >> 4, c4 = tid & 15;
      const float4 v = *(const float4*)(actn + ((size_t)(g * BBr + m) * Tt + t) * NACT + c4 * 4);
      uint2 p;
      p.x = (unsigned)f2bf(v.x) | ((unsigned)f2bf(v.y) << 16);
      p.y = (unsigned)f2bf(v.z) | ((unsigned)f2bf(v.w) << 16);
      *(uint2*)(&x_s[m * XPAD + NPOS + c4 * 4]) = p;
    }
  };
  auto xacc_compute = [&]() -> f32x4 {   // bias + x-part gates
    f32x4 a;
    { const float bv = bias_s[wn * 16 + cl]; a = (f32x4){bv, bv, bv, bv}; }
    const unsigned short* xrow = &x_s[(wm * 16 + cl) * XPAD + qd * 8];
    #pragma unroll
    for (int j = 0; j < KITX; ++j)
      a = __builtin_amdgcn_mfma_f32_16x16x32_bf16(*(const short8*)(xrow + j * 32),
                                                  wfrag[KITH + j], a, 0, 0, 0);
    return a;
  };
  auto poll = [&](unsigned int tgt) {    // all-parallel flag poll, wave 0 only
    if (tid < 64) {
      int spins = 0;
      for (;;) {
        const unsigned int v = load_wt4(pollflag);
        waitvm0();
        if (__all((int)(v >= tgt))) break;
        if (++spins > 3000000) break;    // wrong-not-hung safety valve
      }
    }
    __syncthreads();
  };

  // ---- prologue: publish h_{-1}, stage x_0, precompute xacc_0 ----
  waitvm0();
  __syncthreads();
  if (tid == 0) store_wt4(myflag, 1u);
  stage_x(0);
  __syncthreads();
  f32x4 xacc = xacc_compute();
  poll(1u);

  for (int t = 0; t < Tt; ++t) {
    const unsigned short* hsrc = (t & 1) ? hb1 : hb0;  // h_{t-1}
    unsigned short* hdst       = (t & 1) ? hb0 : hb1;  // h_t

    // 1. load group's h (32KB contiguous, coherent) -> LDS
    u32x4 hv[4];
    #pragma unroll
    for (int it = 0; it < 4; ++it) {
      const int i = tid + BDIM * it;                   // 16B chunk id, 0..2047
      hv[it] = load_wt16(hsrc + grpbase + (size_t)i * 8);
    }
    waitvm0();
    #pragma unroll
    for (int it = 0; it < 4; ++it) {
      const int i = tid + BDIM * it;
      // chunk i -> slot jb_s=i>>6, row=(i>>1)&31, r0=(i&1)*8 ; dim = jb_s*16+r0
      *(u32x4*)(&h_s[((i >> 1) & 31) * HPAD + (i >> 6) * 16 + (i & 1) * 8]) = hv[it];
    }
    __syncthreads();

    // 2. h-part MFMA (16 K-iters) on top of carried x-part acc
    f32x4 acc = xacc;
    const unsigned short* arow = &h_s[(wm * 16 + cl) * HPAD + qd * 8];
    #pragma unroll
    for (int kk = 0; kk < KITH; ++kk)
      acc = __builtin_amdgcn_mfma_f32_16x16x32_bf16(*(const short8*)(arow + kk * 32),
                                                    wfrag[kk], acc, 0, 0, 0);
    #pragma unroll
    for (int rg = 0; rg < 4; ++rg)                     // D: row=qd*4+rg, col=cl
      gates_s[(wm * 16 + qd * 4 + rg) * GPAD + wn * 16 + cl] = acc[rg];
    __syncthreads();

    // 3. LSTM elementwise (i,f,g,o); h_t -> contiguous write-through slice
    {
      const int m = tid >> 4, r = tid & 15;
      const float gi = gates_s[m * GPAD + r];
      const float gf = gates_s[m * GPAD + 16 + r];
      const float gg = gates_s[m * GPAD + 32 + r];
      const float go = gates_s[m * GPAD + 48 + r];
      const float cp = c_s[tid];
      const float iv = sigm(gi), fv = sigm(gf);
      const float gv = tanh_fast(gg), ov = sigm(go);
      const float cn = fv * cp + iv * gv;
      const float hn = ov * tanh_fast(cn);
      c_s[tid] = cn;
      store_wt2(hdst + slotbase + tid, f2bf(hn));
    }
    waitvm0();          // per-wave drain of h stores
    __syncthreads();    // all waves drained
    if (tid == 0) store_wt4(myflag, (unsigned int)(t + 2));

    // 4. barrier window: out[t-1], stage x_{t+1}, x-part MFMA for t+1
    if (jb == 0 && t > 0 && tid < 256) {
      const int m = tid >> 3, l8 = tid & 7;
      const unsigned short* hr = &h_s[m * HPAD + l8 * 64];   // h_{t-1}
      const float* wr = &wout_s[l8 * 64];
      float sum = 0.f;
      #pragma unroll 8
      for (int e = 0; e < 64; ++e) sum += bf2f(hr[e]) * wr[e];
      sum += __shfl_down(sum, 4, 64);
      sum += __shfl_down(sum, 2, 64);
      sum += __shfl_down(sum, 1, 64);
      if (l8 == 0) out[(size_t)(g * BBr + m) * Tt + (t - 1)] = sum + bout;
    }
    if (t + 1 < Tt) {
      stage_x(t + 1);
      __syncthreads();
      xacc = xacc_compute();
    } else {
      __syncthreads();
    }

    // 5. wait for whole group's h_t
    poll((unsigned int)(t + 2));
  }

  // final column: h_{T-1} in hb0 (T even), block-major layout
  if (jb == 0 && tid < 256) {
    const int m = tid >> 3, l8 = tid & 7;
    u32x4 hvv[8];
    #pragma unroll
    for (int it = 0; it < 8; ++it) {
      const size_t a = grpbase + (size_t)((l8 * 4 + (it >> 1)) * BBr + m) * HHd + (it & 1) * 8;
      hvv[it] = load_wt16(hb0 + a);
    }
    waitvm0();
    float sum = 0.f;
    #pragma unroll
    for (int it = 0; it < 8; ++it) {
      const int d0 = l8 * 64 + (it >> 1) * 16 + (it & 1) * 8;
      #pragma unroll
      for (int j = 0; j < 4; ++j) {
        const unsigned u = hvv[it][j];
        sum += bf2f((unsigned short)(u & 0xffffu)) * wout_s[d0 + j * 2];
        sum += bf2f((unsigned short)(u >> 16))     * wout_s[d0 + j * 2 + 1];
      }
    }
    sum += __shfl_down(sum, 4, 64);
    sum += __shfl_down(sum, 2, 64);
    sum += __shfl_down(sum, 1, 64);
    if (l8 == 0) out[(size_t)(g * BBr + m) * Tt + (Tt - 1)] = sum + bout;
  }
}

extern "C" void kernel_launch(void* const* d_in, const int* in_sizes, int n_in,
                              void* d_out, int out_size, void* d_ws, size_t ws_size,
                              hipStream_t stream) {
  const float* obs   = (const float*)d_in[0];
  const float* actn  = (const float*)d_in[1];
  const float* h0    = (const float*)d_in[2];
  const float* c0    = (const float*)d_in[3];
  const float* W_ih  = (const float*)d_in[4];
  const float* W_hh  = (const float*)d_in[5];
  const float* b_ih  = (const float*)d_in[6];
  const float* b_hh  = (const float*)d_in[7];
  const float* W_out = (const float*)d_in[8];
  const float* b_out = (const float*)d_in[9];
  float* out = (float*)d_out;

  unsigned short* hbuf = (unsigned short*)d_ws;            // 2 x 256x512 bf16 = 512KB
  const size_t hbytes = (size_t)2 * Bb * Hh * sizeof(unsigned short);
  unsigned int* flags = (unsigned int*)((char*)d_ws + hbytes);  // 256 x 128B = 32KB

  hipMemsetAsync(flags, 0, 256 * 32 * sizeof(unsigned int), stream);  // ws is 0xAA-poisoned

  hipFuncSetAttribute((const void*)lstm_kernel,
                      hipFuncAttributeMaxDynamicSharedMemorySize, 28672);
  hipLaunchKernelGGL(lstm_kernel, dim3(256), dim3(BDIM), 28672, stream,
                     obs, actn, h0, c0, W_ih, W_hh, b_ih, b_hh, W_out, b_out,
                     out, hbuf, flags);
}